// Round 5
// baseline (2262.123 us; speedup 1.0000x reference)
//
#include <hip/hip_runtime.h>
#include <hip/hip_bf16.h>
#include <math.h>

#define NLAT_I 240
#define NLON_I 480
#define NLAT_O 361
#define NLON_O 720
#define CI_N 32
#define CO_N 32
#define K_N 7
#define WOFF 10
#define WLAT 21

#define PI_F 3.14159265358979323846f
#define TWOPI_F 6.28318530717958647692f
#define DLAT_V (PI_F / 360.0f)
#define DPHI_V (TWOPI_F / 720.0f)
#define CUTOFF_V (3.25f * PI_F / 120.0f)
#define DR_V (CUTOFF_V / 3.0f)
#define IDR_V (1.0f / DR_V)
#define DPH_V (TWOPI_F / 3.0f)
#define IDPH_V (1.0f / DPH_V)
#define QF_V (DLAT_V * DPHI_V)

#define WP 820          // psi LDS width (worst case B=360: BOFF+B+47 = 819)
#define CT 64           // chunks per work item
#define NBLK 768
#define HSTRIDE 8317440 // 32*361*720 (elements per k-plane of H)

typedef __attribute__((ext_vector_type(4))) short short4v;
typedef __attribute__((ext_vector_type(8))) short short8v;
typedef __attribute__((ext_vector_type(16))) float f32x16;

__device__ __forceinline__ unsigned short f2bf(float f) {
  __hip_bfloat16 h = __float2bfloat16(f);   // RTNE
  union { __hip_bfloat16 b; unsigned short s; } u; u.b = h; return u.s;
}

// ---------------- psi evaluation --------------------------------------------
__device__ __forceinline__ void psi_eval(float ct, float st, float cg, float sg,
                                         float q, float bang, float v[7]) {
  float sb, cb;
  sincosf(bang, &sb, &cb);
  float dx = sg * cb - st;
  float dy = sg * sb;
  float dz = cg - ct;
  float c2 = dx * dx + dy * dy + dz * dz;
  float r = 2.0f * asinf(fminf(1.0f, 0.5f * sqrtf(c2)));
  if (r <= CUTOFF_V) {
    float xx = ct * cb * sg - st * cg;
    float yy = sb * sg;
    float phi = atan2f(yy, xx);
    if (phi < 0.0f) phi += TWOPI_F;
    v[0] = fmaxf(0.0f, 1.0f - r * IDR_V) * q;
#pragma unroll
    for (int k = 1; k < 7; ++k) {
      const float irdr = (float)(1 + (k - 1) / 3) * DR_V;
      const float ipph = (float)((k - 1) % 3) * DPH_V;
      float rad = fmaxf(0.0f, 1.0f - fabsf(r - irdr) * IDR_V);
      float dd = fabsf(phi - ipph);
      dd = fminf(dd, TWOPI_F - dd);
      float az = fmaxf(0.0f, 1.0f - dd * IDPH_V);
      v[k] = rad * az * q;
    }
  } else {
#pragma unroll
    for (int k = 0; k < 7; ++k) v[k] = 0.0f;
  }
}

// per-(t,d) lon window half-width: -1 empty, 360 full circle
__device__ __forceinline__ int windowB(int t, int d) {
  int tp = t + d - WOFF;
  if (tp < 0 || tp > NLAT_O - 1) return -1;
  float th = (float)t * DLAT_V, ga = (float)tp * DLAT_V;
  float st = sinf(th), ct = cosf(th), sg = sinf(ga), cg = cosf(ga);
  float den = st * sg;
  float num = cosf(CUTOFF_V) - ct * cg;
  if (den < 1e-9f) return (fabsf(th - ga) <= CUTOFF_V) ? 360 : -1;
  if (num >= den) return -1;
  if (num <= -den) return 360;
  int B = (int)ceilf(acosf(num / den) * (1.0f / DPHI_V)) + 1;  // +1 margin; psi masks
  return B > 360 ? 360 : B;
}

// ---------------- kernel 1: bilinear upsample (f32) -------------------------
__global__ void upsample_kernel(const float* __restrict__ x, float* __restrict__ xu,
                                int* __restrict__ counter) {
  if (blockIdx.x == 0 && threadIdx.x == 0) *counter = 0;
  int idx = blockIdx.x * 256 + threadIdx.x;
  if (idx >= CI_N * NLAT_O * NLON_O) return;
  int p = idx % NLON_O;
  int r = idx / NLON_O;
  int t = r % NLAT_O;
  int i = r / NLAT_O;

  double post = (double)t * (239.0 / 360.0);
  int i0 = (int)floor(post);
  if (i0 < 0) i0 = 0;
  if (i0 > NLAT_I - 1) i0 = NLAT_I - 1;
  int i1 = i0 + 1; if (i1 > NLAT_I - 1) i1 = NLAT_I - 1;
  float wt = (float)(post - (double)i0);

  double posp = (double)p * (2.0 / 3.0);
  double j0f = floor(posp);
  int j0 = ((int)j0f) % NLON_I;
  int j1 = (j0 + 1) % NLON_I;
  float wp = (float)(posp - j0f);

  const float* xi = x + (size_t)i * (NLAT_I * NLON_I);
  float a = xi[i0 * NLON_I + j0];
  float b = xi[i0 * NLON_I + j1];
  float cc = xi[i1 * NLON_I + j0];
  float d = xi[i1 * NLON_I + j1];
  float l0 = (1.0f - wt) * a + wt * cc;
  float l1 = (1.0f - wt) * b + wt * d;
  xu[idx] = (1.0f - wp) * l0 + wp * l1;
}

// ---------------- kernel 2: per-(k,t) normalization scales ------------------
__global__ void scale_kernel(float* __restrict__ recip) {
  int t = blockIdx.x;
  int tid = threadIdx.x;
  float th = (float)t * DLAT_V;
  float st, ct;
  sincosf(th, &st, &ct);
  float acc[7];
#pragma unroll
  for (int k = 0; k < 7; ++k) acc[k] = 0.0f;

  for (int d = 0; d < WLAT; ++d) {
    int tp = t + d - WOFF;
    if (tp < 0 || tp > NLAT_O - 1) continue;
    float ga = (float)tp * DLAT_V;
    float sg, cg;
    sincosf(ga, &sg, &cg);
    float q = sg * QF_V;
    for (int jj = tid; jj < NLON_O; jj += 256) {
      float v[7];
      psi_eval(ct, st, cg, sg, q, (float)jj * DPHI_V, v);
#pragma unroll
      for (int k = 0; k < 7; ++k) acc[k] += v[k];
    }
  }
#pragma unroll
  for (int k = 0; k < 7; ++k) {
    float a = acc[k];
    for (int off = 32; off > 0; off >>= 1) a += __shfl_down(a, off, 64);
    acc[k] = a;
  }
  __shared__ float red[4][7];
  int wid = tid >> 6;
  if ((tid & 63) == 0) {
#pragma unroll
    for (int k = 0; k < 7; ++k) red[wid][k] = acc[k];
  }
  __syncthreads();
  if (tid == 0) {
#pragma unroll
    for (int k = 0; k < 7; ++k) {
      float s = red[0][k] + red[1][k] + red[2][k] + red[3][k];
      recip[t * 7 + k] = 1.0f / fmaxf(s, 1e-8f);
    }
  }
}

// ---------------- kernel 3: H[k,o,t,b] = sum_i w[o,i,k] xu[i,t,b] (bf16) ----
__global__ __launch_bounds__(256) void hgemm_kernel(
    const float* __restrict__ xu, const float* __restrict__ w,
    unsigned short* __restrict__ H) {
  const int t = blockIdx.x;
  const int b0blk = blockIdx.y * 128;
  const int tid = threadIdx.x;
  __shared__ __align__(16) unsigned short s_w[7 * 32 * 32];   // [k][o][i]
  __shared__ __align__(16) unsigned short s_x[128 * 40];      // [b][i] (pad 40)

  for (int idx = tid; idx < 7168; idx += 256) {
    int k = idx >> 10; int rem = idx & 1023; int o = rem >> 5; int i = rem & 31;
    s_w[(k * 32 + o) * 32 + i] = f2bf(w[(o * 32 + i) * 7 + k]);
  }
  for (int idx = tid; idx < 32 * 128; idx += 256) {
    int b = idx & 127; int i = idx >> 7;
    int gb = b0blk + b; if (gb > 719) gb = 719;
    s_x[b * 40 + i] = f2bf(xu[(i * NLAT_O + t) * NLON_O + gb]);
  }
  __syncthreads();

  const int lane = tid & 63;
  const int wv = tid >> 6;
  const int bsub = wv * 32;
  const int g8 = (lane >> 5) * 8;
  const int nn = lane & 31;

  for (int k = 0; k < 7; ++k) {
    f32x16 D;
#pragma unroll
    for (int z = 0; z < 16; ++z) D[z] = 0.0f;
    short8v A0 = *(const short8v*)&s_w[(k * 32 + nn) * 32 + g8];
    short8v B0 = *(const short8v*)&s_x[(bsub + nn) * 40 + g8];
    D = __builtin_amdgcn_mfma_f32_32x32x16_bf16(A0, B0, D, 0, 0, 0);
    short8v A1 = *(const short8v*)&s_w[(k * 32 + nn) * 32 + 16 + g8];
    short8v B1 = *(const short8v*)&s_x[(bsub + nn) * 40 + 16 + g8];
    D = __builtin_amdgcn_mfma_f32_32x32x16_bf16(A1, B1, D, 0, 0, 0);
    int b = b0blk + bsub + nn;
    if (b < NLON_O) {
#pragma unroll
      for (int rr = 0; rr < 16; ++rr) {
        int o = (rr & 3) + 8 * (rr >> 2) + 4 * (lane >> 5);
        H[((k * 32 + o) * NLAT_O + t) * NLON_O + b] = f2bf(D[rr]);
      }
    }
  }
}

// ---------------- kernel 4: MFMA sparse correlation y = psi (*) H -----------
__global__ void disco_kernel(const unsigned short* __restrict__ H,
                             const float* __restrict__ recip,
                             float* __restrict__ y, int* __restrict__ counter) {
  const int tid = threadIdx.x;
  __shared__ __align__(16) short sh_psi[4 * 7 * WP];  // [shift r][k][j]
  __shared__ int Sbuf[362];
  __shared__ int sB[WLAT], sUc[WLAT + 1], sCmin[WLAT], sBOFF[WLAT];
  __shared__ float rc[7];
  __shared__ int curItem;

  // ---- schedule: weight(t) = total chunk count; items = (t, pblk, part) ----
  for (int j = tid; j < 361; j += 256) {
    int t = (j & 1) ? 360 - (j >> 1) : (j >> 1);   // poles first
    int Wt = 0;
    for (int d = 0; d < WLAT; ++d) {
      int B = windowB(t, d);
      if (B >= 0) Wt += ((31 + B) >> 4) + ((B + 15) >> 4) + 1;
    }
    Sbuf[j] = 2 * ((Wt + CT - 1) / CT);
  }
  __syncthreads();
  if (tid == 0) {
    int run = 0;
    for (int j = 0; j < 361; ++j) { int v = Sbuf[j]; Sbuf[j] = run; run += v; }
    Sbuf[361] = run;
  }
  __syncthreads();
  const int NTOT = Sbuf[361];

  const int lane = tid & 63;
  const int wv = tid >> 6;
  const int nn = lane & 31;
  const int g8 = (lane >> 5) * 8;

  while (true) {
    if (tid == 0) curItem = atomicAdd(counter, 1);
    __syncthreads();
    const int m = curItem;
    if (m >= NTOT) break;

    int lo = 0, hi = 360;
    while (lo < hi) {
      int mid = (lo + hi + 1) >> 1;
      if (Sbuf[mid] <= m) lo = mid; else hi = mid - 1;
    }
    const int j = lo;
    const int r = m - Sbuf[j];
    const int t = (j & 1) ? 360 - (j >> 1) : (j >> 1);
    const int pblk = r & 1;
    const int part = r >> 1;

    if (tid < WLAT) {
      int B = windowB(t, tid);
      sB[tid] = B;
      sBOFF[tid] = (B + 52) & ~3;
      sCmin[tid] = (B >= 0) ? -((B + 15) >> 4) : 0;
    }
    if (tid < 7) rc[tid] = recip[t * 7 + tid];
    __syncthreads();
    if (tid == 0) {
      int run = 0; sUc[0] = 0;
      for (int d = 0; d < WLAT; ++d) {
        int B = sB[d];
        int nc = (B >= 0) ? ((31 + B) >> 4) + ((B + 15) >> 4) + 1 : 0;
        run += nc; sUc[d + 1] = run;
      }
    }
    __syncthreads();
    const int Wt = sUc[WLAT];
    int g0 = part * CT;
    int g1 = g0 + CT; if (g1 > Wt) g1 = Wt;

    const int p0w = pblk * 384 + wv * 96;
    f32x16 acc0, acc1, acc2;
#pragma unroll
    for (int z = 0; z < 16; ++z) { acc0[z] = 0.0f; acc1[z] = 0.0f; acc2[z] = 0.0f; }

    float tht = (float)t * DLAT_V;
    float stv, ctv;
    sincosf(tht, &stv, &ctv);

    const int rowoff = nn * (NLAT_O * NLON_O) + g8;

    int dcur = -1;
    for (int gi = g0; gi < g1; ++gi) {
      int d = (dcur < 0) ? 0 : dcur;
      while (sUc[d + 1] <= gi) ++d;
      if (d != dcur) {
        __syncthreads();
        {  // zero psi region
          int4 zz = make_int4(0, 0, 0, 0);
          int4* z4 = (int4*)sh_psi;
          for (int idx = tid; idx < (4 * 7 * WP) / 8; idx += 256) z4[idx] = zz;
        }
        __syncthreads();
        const int B = sB[d];
        const int BOFF = sBOFF[d];
        const int tpd = t + d - WOFF;
        float ga = (float)tpd * DLAT_V;
        float sgv, cgv;
        sincosf(ga, &sgv, &cgv);
        float q = sgv * QF_V;
        int bLo = -B;
        int bHi = (B >= 360) ? 359 : B;   // avoid double-count at +-360
        int nsup = bHi - bLo + 1;
        for (int ix = tid; ix < nsup; ix += 256) {
          int beta = bLo + ix;
          float v[7];
          psi_eval(ctv, stv, cgv, sgv, q, (float)beta * DPHI_V, v);
          unsigned short vb[7];
#pragma unroll
          for (int k = 0; k < 7; ++k) vb[k] = f2bf(v[k] * rc[k]);
#pragma unroll
          for (int rr2 = 0; rr2 < 4; ++rr2) {
            int jp = beta + BOFF - rr2;
#pragma unroll
            for (int k = 0; k < 7; ++k)
              sh_psi[(rr2 * 7 + k) * WP + jp] = (short)vb[k];
          }
        }
        __syncthreads();
        dcur = d;
      }
      const int c = sCmin[d] + (gi - sUc[d]);
      const int tpd = t + d - WOFF;

      // B-fragment base (shift-select: 8B-aligned by construction)
      int jb = c * 16 + g8 - nn + sBOFF[d];
      int rsel = jb & 3;
      int e = jb - rsel;
      const short* prow = &sh_psi[rsel * 7 * WP + e];

      // A-tile column bases (wrap mod 720; all multiples of 16)
      int xb = p0w + c * 16;
      int b0 = xb; if (b0 < 0) b0 += 720; if (b0 >= 720) b0 -= 720;
      int b1 = b0 + 32; if (b1 >= 720) b1 -= 720;
      int b2 = b1 + 32; if (b2 >= 720) b2 -= 720;

      const unsigned short* hrow = H + rowoff + tpd * NLON_O;

#pragma unroll
      for (int k = 0; k < 7; ++k) {
        short4v blo = *(const short4v*)(prow + k * WP);
        short4v bhi = *(const short4v*)(prow + k * WP + 4);
        short8v Bf;
#pragma unroll
        for (int q4 = 0; q4 < 4; ++q4) { Bf[q4] = blo[q4]; Bf[4 + q4] = bhi[q4]; }
        const unsigned short* hk = hrow + k * HSTRIDE;
        short8v A0 = *(const short8v*)(hk + b0);
        acc0 = __builtin_amdgcn_mfma_f32_32x32x16_bf16(A0, Bf, acc0, 0, 0, 0);
        short8v A1 = *(const short8v*)(hk + b1);
        acc1 = __builtin_amdgcn_mfma_f32_32x32x16_bf16(A1, Bf, acc1, 0, 0, 0);
        short8v A2 = *(const short8v*)(hk + b2);
        acc2 = __builtin_amdgcn_mfma_f32_32x32x16_bf16(A2, Bf, acc2, 0, 0, 0);
      }
    }

    // ---- store: y[o, t, p] += acc (atomic merge across d-parts) ----
    auto storeAcc = [&](f32x16& A, int a) {
      int p = p0w + a * 32 + nn;
      if (p < NLON_O) {
#pragma unroll
        for (int rr = 0; rr < 16; ++rr) {
          int o = (rr & 3) + 8 * (rr >> 2) + 4 * (lane >> 5);
          atomicAdd(&y[(o * NLAT_O + t) * NLON_O + p], A[rr]);
        }
      }
    };
    storeAcc(acc0, 0);
    storeAcc(acc1, 1);
    storeAcc(acc2, 2);
  }
}

// ---------------- launch ----------------------------------------------------
extern "C" void kernel_launch(void* const* d_in, const int* in_sizes, int n_in,
                              void* d_out, int out_size, void* d_ws, size_t ws_size,
                              hipStream_t stream) {
  (void)in_sizes; (void)n_in; (void)out_size; (void)ws_size;
  const float* x = (const float*)d_in[0];
  const float* w = (const float*)d_in[1];
  float* y = (float*)d_out;

  // workspace: xu f32 (33.3 MB) | H bf16 (116.4 MB) | recip | counter (~150 MB)
  float* xu = (float*)d_ws;
  unsigned short* H = (unsigned short*)(xu + (size_t)CI_N * NLAT_O * NLON_O);
  float* recip = (float*)(H + (size_t)K_N * CO_N * NLAT_O * NLON_O);
  int* counter = (int*)(recip + NLAT_O * K_N);

  hipMemsetAsync(y, 0, (size_t)CO_N * NLAT_O * NLON_O * sizeof(float), stream);

  int n_up = CI_N * NLAT_O * NLON_O;
  upsample_kernel<<<(n_up + 255) / 256, 256, 0, stream>>>(x, xu, counter);
  scale_kernel<<<NLAT_O, 256, 0, stream>>>(recip);
  hgemm_kernel<<<dim3(NLAT_O, 6), 256, 0, stream>>>(xu, w, H);
  disco_kernel<<<NBLK, 256, 0, stream>>>(H, recip, y, counter);
}

// Round 6
// 1000.052 us; speedup vs baseline: 2.2620x; 2.2620x over previous
//
#include <hip/hip_runtime.h>
#include <hip/hip_bf16.h>
#include <math.h>

#define NLAT_I 240
#define NLON_I 480
#define NLAT_O 361
#define NLON_O 720
#define CI_N 32
#define CO_N 32
#define K_N 7
#define WOFF 10
#define WLAT 21

#define PI_F 3.14159265358979323846f
#define TWOPI_F 6.28318530717958647692f
#define DLAT_V (PI_F / 360.0f)
#define DPHI_V (TWOPI_F / 720.0f)
#define CUTOFF_V (3.25f * PI_F / 120.0f)
#define DR_V (CUTOFF_V / 3.0f)
#define IDR_V (1.0f / DR_V)
#define DPH_V (TWOPI_F / 3.0f)
#define IDPH_V (1.0f / DPH_V)
#define QF_V (DLAT_V * DPHI_V)

#define WP 840          // psi LDS row width (max frag read 2B+113 = 833 at B=360)
#define CT 64           // positions per work item
#define NBLK 1024
#define NC45 45         // 720/16 column chunks

typedef __attribute__((ext_vector_type(4))) short short4v;
typedef __attribute__((ext_vector_type(8))) short short8v;
typedef __attribute__((ext_vector_type(16))) float f32x16;

__device__ __forceinline__ unsigned short f2bf(float f) {
  __hip_bfloat16 h = __float2bfloat16(f);   // RTNE
  union { __hip_bfloat16 b; unsigned short s; } u; u.b = h; return u.s;
}

// ---------------- psi evaluation --------------------------------------------
__device__ __forceinline__ void psi_eval(float ct, float st, float cg, float sg,
                                         float q, float bang, float v[7]) {
  float sb, cb;
  sincosf(bang, &sb, &cb);
  float dx = sg * cb - st;
  float dy = sg * sb;
  float dz = cg - ct;
  float c2 = dx * dx + dy * dy + dz * dz;
  float r = 2.0f * asinf(fminf(1.0f, 0.5f * sqrtf(c2)));
  if (r <= CUTOFF_V) {
    float xx = ct * cb * sg - st * cg;
    float yy = sb * sg;
    float phi = atan2f(yy, xx);
    if (phi < 0.0f) phi += TWOPI_F;
    v[0] = fmaxf(0.0f, 1.0f - r * IDR_V) * q;
#pragma unroll
    for (int k = 1; k < 7; ++k) {
      const float irdr = (float)(1 + (k - 1) / 3) * DR_V;
      const float ipph = (float)((k - 1) % 3) * DPH_V;
      float rad = fmaxf(0.0f, 1.0f - fabsf(r - irdr) * IDR_V);
      float dd = fabsf(phi - ipph);
      dd = fminf(dd, TWOPI_F - dd);
      float az = fmaxf(0.0f, 1.0f - dd * IDPH_V);
      v[k] = rad * az * q;
    }
  } else {
#pragma unroll
    for (int k = 0; k < 7; ++k) v[k] = 0.0f;
  }
}

// per-(t,d) lon window half-width: -1 empty, 360 full circle
__device__ __forceinline__ int windowB(int t, int d) {
  int tp = t + d - WOFF;
  if (tp < 0 || tp > NLAT_O - 1) return -1;
  float th = (float)t * DLAT_V, ga = (float)tp * DLAT_V;
  float st = sinf(th), ct = cosf(th), sg = sinf(ga), cg = cosf(ga);
  float den = st * sg;
  float num = cosf(CUTOFF_V) - ct * cg;
  if (den < 1e-9f) return (fabsf(th - ga) <= CUTOFF_V) ? 360 : -1;
  if (num >= den) return -1;
  if (num <= -den) return 360;
  int B = (int)ceilf(acosf(num / den) * (1.0f / DPHI_V)) + 1;  // +1 margin; psi masks
  return B > 360 ? 360 : B;
}

// ---------------- kernel 0: prep (w2 tiles, psi offsets, counter) -----------
__global__ void prep_kernel(const float* __restrict__ w, unsigned short* __restrict__ w2,
                            int* __restrict__ offs, int* __restrict__ counter) {
  int tid = threadIdx.x;
  if (tid == 0) *counter = 0;
  // w2[c16][o][kk] = bf16(w[o][i][k]) with ci=c16*16+kk, k=ci>>5, i=ci&31
  for (int idx = tid; idx < 14 * 32 * 16; idx += 256) {
    int kk = idx & 15; int o = (idx >> 4) & 31; int c16 = idx >> 9;
    int ci = c16 * 16 + kk; int i = ci & 31; int k = ci >> 5;
    w2[idx] = f2bf(w[(o * 32 + i) * 7 + k]);
  }
  for (int e = tid; e < 361 * 21; e += 256) {
    int t = e / 21, d = e % 21;
    int B = windowB(t, d);
    offs[e] = (B >= 0) ? 7 * ((B >= 360) ? 720 : 2 * B + 1) : 0;
  }
  __syncthreads();
  if (tid == 0) {
    int run = 0;
    for (int e = 0; e < 361 * 21; ++e) { int v = offs[e]; offs[e] = run; run += v; }
    offs[361 * 21] = run;
  }
}

// ---------------- kernel 1: bilinear upsample -> tiled bf16 XT --------------
// XT[t][c][i][kk] with b = c*16+kk  (wave A-load = contiguous 1KB)
__global__ void upsample_kernel(const float* __restrict__ x,
                                unsigned short* __restrict__ XT) {
  int idx = blockIdx.x * 256 + threadIdx.x;
  if (idx >= NLAT_O * NC45 * 512) return;
  int kk = idx & 15;
  int i = (idx >> 4) & 31;
  int c = (idx >> 9) % NC45;
  int t = idx / (NC45 * 512);
  int p = c * 16 + kk;

  double post = (double)t * (239.0 / 360.0);
  int i0 = (int)floor(post);
  if (i0 < 0) i0 = 0;
  if (i0 > NLAT_I - 1) i0 = NLAT_I - 1;
  int i1 = i0 + 1; if (i1 > NLAT_I - 1) i1 = NLAT_I - 1;
  float wt = (float)(post - (double)i0);

  double posp = (double)p * (2.0 / 3.0);
  double j0f = floor(posp);
  int j0 = ((int)j0f) % NLON_I;
  int j1 = (j0 + 1) % NLON_I;
  float wp = (float)(posp - j0f);

  const float* xi = x + (size_t)i * (NLAT_I * NLON_I);
  float a = xi[i0 * NLON_I + j0];
  float b = xi[i0 * NLON_I + j1];
  float cc = xi[i1 * NLON_I + j0];
  float d = xi[i1 * NLON_I + j1];
  float l0 = (1.0f - wt) * a + wt * cc;
  float l1 = (1.0f - wt) * b + wt * d;
  XT[idx] = f2bf((1.0f - wp) * l0 + wp * l1);
}

// ---------------- kernel 2: per-(k,t) normalization scales ------------------
__global__ void scale_kernel(float* __restrict__ recip) {
  int t = blockIdx.x;
  int tid = threadIdx.x;
  float th = (float)t * DLAT_V;
  float st, ct;
  sincosf(th, &st, &ct);
  float acc[7];
#pragma unroll
  for (int k = 0; k < 7; ++k) acc[k] = 0.0f;

  for (int d = 0; d < WLAT; ++d) {
    int tp = t + d - WOFF;
    if (tp < 0 || tp > NLAT_O - 1) continue;
    float ga = (float)tp * DLAT_V;
    float sg, cg;
    sincosf(ga, &sg, &cg);
    float q = sg * QF_V;
    for (int jj = tid; jj < NLON_O; jj += 256) {
      float v[7];
      psi_eval(ct, st, cg, sg, q, (float)jj * DPHI_V, v);
#pragma unroll
      for (int k = 0; k < 7; ++k) acc[k] += v[k];
    }
  }
#pragma unroll
  for (int k = 0; k < 7; ++k) {
    float a = acc[k];
    for (int off = 32; off > 0; off >>= 1) a += __shfl_down(a, off, 64);
    acc[k] = a;
  }
  __shared__ float red[4][7];
  int wid = tid >> 6;
  if ((tid & 63) == 0) {
#pragma unroll
    for (int k = 0; k < 7; ++k) red[wid][k] = acc[k];
  }
  __syncthreads();
  if (tid == 0) {
#pragma unroll
    for (int k = 0; k < 7; ++k) {
      float s = red[0][k] + red[1][k] + red[2][k] + red[3][k];
      recip[t * 7 + k] = 1.0f / fmaxf(s, 1e-8f);
    }
  }
}

// ---------------- kernel 3: precompute normalized psi (bf16) ----------------
// PSI layout per (t,d): [k][nsup], beta = bLo+ix
__global__ void psi_build_kernel(const float* __restrict__ recip,
                                 const int* __restrict__ offs,
                                 unsigned short* __restrict__ PSI) {
  int t = blockIdx.x, d = blockIdx.y;
  int B = windowB(t, d);
  if (B < 0) return;
  int off = offs[t * 21 + d];
  int nsup = (B >= 360) ? 720 : 2 * B + 1;
  int bLo = (B >= 360) ? -360 : -B;
  int tp = t + d - WOFF;
  float th = (float)t * DLAT_V, ga = (float)tp * DLAT_V;
  float st, ct, sg, cg;
  sincosf(th, &st, &ct);
  sincosf(ga, &sg, &cg);
  float q = sg * QF_V;
  float rc[7];
#pragma unroll
  for (int k = 0; k < 7; ++k) rc[k] = recip[t * 7 + k];
  for (int ix = threadIdx.x; ix < nsup; ix += 256) {
    float v[7];
    psi_eval(ct, st, cg, sg, q, (float)(bLo + ix) * DPHI_V, v);
#pragma unroll
    for (int k = 0; k < 7; ++k) PSI[off + k * nsup + ix] = f2bf(v[k] * rc[k]);
  }
}

// ---------------- kernel 4: persistent MFMA conv (G) + channel MFMA (y) -----
#define MAC1(KK, ACC) {                                                   \
    short4v l4 = *(const short4v*)(pr + (KK) * WP);                       \
    short4v h4 = *(const short4v*)(pr + (KK) * WP + 4);                   \
    short8v Bf;                                                           \
    Bf[0]=l4[0]; Bf[1]=l4[1]; Bf[2]=l4[2]; Bf[3]=l4[3];                   \
    Bf[4]=h4[0]; Bf[5]=h4[1]; Bf[6]=h4[2]; Bf[7]=h4[3];                   \
    ACC = __builtin_amdgcn_mfma_f32_32x32x16_bf16(A, Bf, ACC, 0, 0, 0); }

#define DUMPQ(RR) {                                                       \
    int iq = ((RR) & 3) + 8 * ((RR) >> 2) + 4 * g;                        \
    int base = nn * 16 + (iq & 15);                                       \
    b2[0*512+base] = f2bf(acc0[RR]); b2[1*512+base] = f2bf(acc1[RR]);     \
    b2[2*512+base] = f2bf(acc2[RR]); b2[3*512+base] = f2bf(acc3[RR]);     \
    b2[4*512+base] = f2bf(acc4[RR]); b2[5*512+base] = f2bf(acc5[RR]);     \
    b2[6*512+base] = f2bf(acc6[RR]); }

__global__ __launch_bounds__(256) void disco_kernel(
    const unsigned short* __restrict__ XT, const unsigned short* __restrict__ PSI,
    const unsigned short* __restrict__ w2g, const int* __restrict__ offs,
    float* __restrict__ y, int* __restrict__ counter) {
  const int tid = threadIdx.x;
  __shared__ __align__(16) short sh_psi[4 * 7 * WP];   // also reused as b2 region
  __shared__ int Sbuf[362];
  __shared__ int sB[WLAT], sUc[WLAT + 1], sOffT[WLAT];
  __shared__ int curItem;

  // ---- schedule (identical in every block) ----
  for (int j = tid; j < 361; j += 256) {
    int t = (j & 1) ? 360 - (j >> 1) : (j >> 1);   // poles first
    int Wt = 0;
    for (int d = 0; d < WLAT; ++d) {
      int B = windowB(t, d);
      if (B >= 0) Wt += ((31 + B) >> 4) + ((B + 15) >> 4) + 1;
    }
    Sbuf[j] = 6 * ((Wt + CT - 1) / CT);
  }
  __syncthreads();
  if (tid == 0) {
    int run = 0;
    for (int j = 0; j < 361; ++j) { int v = Sbuf[j]; Sbuf[j] = run; run += v; }
    Sbuf[361] = run;
  }
  __syncthreads();
  const int NTOT = Sbuf[361];

  const int lane = tid & 63, wv = tid >> 6, nn = lane & 31, g = lane >> 5;
  const int g8 = g * 8;
  const int laneA = nn * 16 + g8;

  while (true) {
    if (tid == 0) curItem = atomicAdd(counter, 1);
    __syncthreads();
    const int m = curItem;
    if (m >= NTOT) break;

    int lo = 0, hi = 360;
    while (lo < hi) {
      int mid = (lo + hi + 1) >> 1;
      if (Sbuf[mid] <= m) lo = mid; else hi = mid - 1;
    }
    const int j = lo;
    const int r = m - Sbuf[j];
    const int t = (j & 1) ? 360 - (j >> 1) : (j >> 1);
    const int pgroup = r % 6;
    const int part = r / 6;

    if (tid < WLAT) {
      sB[tid] = windowB(t, tid);
      sOffT[tid] = offs[t * 21 + tid];
    }
    __syncthreads();
    if (tid == 0) {
      int run = 0; sUc[0] = 0;
      for (int d = 0; d < WLAT; ++d) {
        int B = sB[d];
        int np = (B >= 0) ? ((31 + B) >> 4) + ((B + 15) >> 4) + 1 : 0;
        run += np; sUc[d + 1] = run;
      }
    }
    __syncthreads();
    const int Wt = sUc[WLAT];
    int g0 = part * CT, g1 = g0 + CT;
    if (g1 > Wt) g1 = Wt;

    const int ptile = pgroup * 4 + wv;   // 0..23 (23 = dead pad tile)
    const int pw = ptile * 32;
    const int pw16 = ptile * 2;

    f32x16 acc0, acc1, acc2, acc3, acc4, acc5, acc6;
#pragma unroll
    for (int z = 0; z < 16; ++z) {
      acc0[z]=0; acc1[z]=0; acc2[z]=0; acc3[z]=0; acc4[z]=0; acc5[z]=0; acc6[z]=0;
    }

    int dcur = -1, B = 0, BOFF = 0, cmin = 0, tpd = 0;
    for (int gi = g0; gi < g1; ++gi) {
      int d = (dcur < 0) ? 0 : dcur;
      while (sUc[d + 1] <= gi) ++d;
      if (d != dcur) {
        __syncthreads();
        {  // zero psi region
          int4 zz = make_int4(0, 0, 0, 0);
          int4* z4 = (int4*)sh_psi;
          for (int ii = tid; ii < (4 * 7 * WP) / 8; ii += 256) z4[ii] = zz;
        }
        __syncthreads();
        B = sB[d];
        BOFF = (B + 64) & ~3;
        cmin = -((B + 15) >> 4);
        tpd = t + d - WOFF;
        const int nsup = (B >= 360) ? 720 : 2 * B + 1;
        const int bLo = (B >= 360) ? -360 : -B;
        const int off = sOffT[d];
        for (int ix = tid; ix < nsup; ix += 256) {
          int jp = bLo + ix + BOFF;
#pragma unroll
          for (int k = 0; k < 7; ++k) {
            short sv = (short)PSI[off + k * nsup + ix];
            sh_psi[(0 * 7 + k) * WP + jp    ] = sv;
            sh_psi[(1 * 7 + k) * WP + jp - 1] = sv;
            sh_psi[(2 * 7 + k) * WP + jp - 2] = sv;
            sh_psi[(3 * 7 + k) * WP + jp - 3] = sv;
          }
        }
        __syncthreads();
        dcur = d;
      }
      const int c = cmin + (gi - sUc[d]);
      int v45 = pw16 + c;
      if (v45 < 0) v45 += NC45;
      if (v45 >= NC45) v45 -= NC45;
      const unsigned short* ap = XT + (((size_t)tpd * NC45 + v45) << 9) + laneA;
      short8v A = *(const short8v*)ap;
      int jb = c * 16 + g8 - nn + BOFF;
      int rsel = jb & 3;
      const short* pr = sh_psi + rsel * (7 * WP) + (jb - rsel);
      MAC1(0, acc0) MAC1(1, acc1) MAC1(2, acc2) MAC1(3, acc3)
      MAC1(4, acc4) MAC1(5, acc5) MAC1(6, acc6)
    }
    __syncthreads();   // all waves done reading sh_psi before b2 reuse

    // ---- GEMM2: y[o,p] = sum_{ci=(k,i)} w2[o,ci] * G[ci,p], via LDS relayout
    unsigned short* b2 = (unsigned short*)sh_psi + wv * 3584;  // 7KB per wave
    f32x16 Dy;
#pragma unroll
    for (int z = 0; z < 16; ++z) Dy[z] = 0.0f;

    {  // half 0: i in [0,16) <-> regs 0..7
#pragma unroll
      for (int q2 = 0; q2 < 8; ++q2) { DUMPQ(q2) }
#pragma unroll
      for (int k2 = 0; k2 < 7; ++k2) {
        short8v A2 = *(const short8v*)(w2g + (((2 * k2 + 0) * 32 + nn) << 4) + g8);
        short8v B2f = *(const short8v*)(b2 + (k2 << 9) + (nn << 4) + g8);
        Dy = __builtin_amdgcn_mfma_f32_32x32x16_bf16(A2, B2f, Dy, 0, 0, 0);
      }
    }
    {  // half 1: i in [16,32) <-> regs 8..15
#pragma unroll
      for (int q2 = 8; q2 < 16; ++q2) { DUMPQ(q2) }
#pragma unroll
      for (int k2 = 0; k2 < 7; ++k2) {
        short8v A2 = *(const short8v*)(w2g + (((2 * k2 + 1) * 32 + nn) << 4) + g8);
        short8v B2f = *(const short8v*)(b2 + (k2 << 9) + (nn << 4) + g8);
        Dy = __builtin_amdgcn_mfma_f32_32x32x16_bf16(A2, B2f, Dy, 0, 0, 0);
      }
    }

    const int p = pw + nn;
    if (p < NLON_O) {
#pragma unroll
      for (int rr = 0; rr < 16; ++rr) {
        int o = (rr & 3) + 8 * (rr >> 2) + 4 * g;
        atomicAdd(&y[((size_t)o * NLAT_O + t) * NLON_O + p], Dy[rr]);
      }
    }
  }
}

// ---------------- launch ----------------------------------------------------
extern "C" void kernel_launch(void* const* d_in, const int* in_sizes, int n_in,
                              void* d_out, int out_size, void* d_ws, size_t ws_size,
                              hipStream_t stream) {
  (void)in_sizes; (void)n_in; (void)out_size; (void)ws_size;
  const float* x = (const float*)d_in[0];
  const float* w = (const float*)d_in[1];
  float* y = (float*)d_out;

  // ws: XT bf16 (16.6MB) | PSI bf16 (11.2MB cap) | w2 | recip | offs | counter
  unsigned short* XT = (unsigned short*)d_ws;                 // 361*45*512
  unsigned short* PSI = XT + (size_t)NLAT_O * NC45 * 512;     // cap 5.6e6
  unsigned short* w2 = PSI + 5600000;                         // 14*32*16
  float* recip = (float*)(w2 + 7168);                         // 361*7
  int* offs = (int*)(recip + NLAT_O * K_N);                   // 361*21+1
  int* counter = offs + 361 * 21 + 1;

  hipMemsetAsync(y, 0, (size_t)CO_N * NLAT_O * NLON_O * sizeof(float), stream);

  prep_kernel<<<1, 256, 0, stream>>>(w, w2, offs, counter);
  int n_up = NLAT_O * NC45 * 512;
  upsample_kernel<<<(n_up + 255) / 256, 256, 0, stream>>>(x, XT);
  scale_kernel<<<NLAT_O, 256, 0, stream>>>(recip);
  psi_build_kernel<<<dim3(NLAT_O, WLAT), 256, 0, stream>>>(recip, offs, PSI);
  disco_kernel<<<NBLK, 256, 0, stream>>>(XT, PSI, w2, offs, y, counter);
}

// Round 7
// 894.031 us; speedup vs baseline: 2.5303x; 1.1186x over previous
//
#include <hip/hip_runtime.h>
#include <hip/hip_bf16.h>
#include <math.h>

#define NLAT_I 240
#define NLON_I 480
#define NLAT_O 361
#define NLON_O 720
#define CI_N 32
#define CO_N 32
#define K_N 7
#define WOFF 10
#define WLAT 21

#define PI_F 3.14159265358979323846f
#define TWOPI_F 6.28318530717958647692f
#define DLAT_V (PI_F / 360.0f)
#define DPHI_V (TWOPI_F / 720.0f)
#define CUTOFF_V (3.25f * PI_F / 120.0f)
#define DR_V (CUTOFF_V / 3.0f)
#define IDR_V (1.0f / DR_V)
#define DPH_V (TWOPI_F / 3.0f)
#define IDPH_V (1.0f / DPH_V)
#define QF_V (DLAT_V * DPHI_V)

#define PAD_T 64        // Toeplitz pad (covers fragment reach beyond support)
#define CT 64           // positions per work item
#define NBLK 768
#define NC45 45         // 720/16 column chunks
#define NE 7581         // 361*21

typedef __attribute__((ext_vector_type(8))) short short8v;
typedef __attribute__((ext_vector_type(16))) float f32x16;

__device__ __forceinline__ unsigned short f2bf(float f) {
  __hip_bfloat16 h = __float2bfloat16(f);   // RTNE
  union { __hip_bfloat16 b; unsigned short s; } u; u.b = h; return u.s;
}

// ---------------- psi evaluation --------------------------------------------
__device__ __forceinline__ void psi_eval(float ct, float st, float cg, float sg,
                                         float q, float bang, float v[7]) {
  float sb, cb;
  sincosf(bang, &sb, &cb);
  float dx = sg * cb - st;
  float dy = sg * sb;
  float dz = cg - ct;
  float c2 = dx * dx + dy * dy + dz * dz;
  float r = 2.0f * asinf(fminf(1.0f, 0.5f * sqrtf(c2)));
  if (r <= CUTOFF_V) {
    float xx = ct * cb * sg - st * cg;
    float yy = sb * sg;
    float phi = atan2f(yy, xx);
    if (phi < 0.0f) phi += TWOPI_F;
    v[0] = fmaxf(0.0f, 1.0f - r * IDR_V) * q;
#pragma unroll
    for (int k = 1; k < 7; ++k) {
      const float irdr = (float)(1 + (k - 1) / 3) * DR_V;
      const float ipph = (float)((k - 1) % 3) * DPH_V;
      float rad = fmaxf(0.0f, 1.0f - fabsf(r - irdr) * IDR_V);
      float dd = fabsf(phi - ipph);
      dd = fminf(dd, TWOPI_F - dd);
      float az = fmaxf(0.0f, 1.0f - dd * IDPH_V);
      v[k] = rad * az * q;
    }
  } else {
#pragma unroll
    for (int k = 0; k < 7; ++k) v[k] = 0.0f;
  }
}

// per-(t,d) lon window half-width: -1 empty, 360 full circle
__device__ __forceinline__ int windowB(int t, int d) {
  int tp = t + d - WOFF;
  if (tp < 0 || tp > NLAT_O - 1) return -1;
  float th = (float)t * DLAT_V, ga = (float)tp * DLAT_V;
  float st = sinf(th), ct = cosf(th), sg = sinf(ga), cg = cosf(ga);
  float den = st * sg;
  float num = cosf(CUTOFF_V) - ct * cg;
  if (den < 1e-9f) return (fabsf(th - ga) <= CUTOFF_V) ? 360 : -1;
  if (num >= den) return -1;
  if (num <= -den) return 360;
  int B = (int)ceilf(acosf(num / den) * (1.0f / DPHI_V)) + 1;  // +1 margin; psi masks
  return B > 360 ? 360 : B;
}

__device__ __forceinline__ int nsupOf(int B) { return (B >= 360) ? 720 : 2 * B + 1; }
__device__ __forceinline__ int widthOf(int B) {
  return (B < 0) ? 0 : ((nsupOf(B) + 129) & ~1);   // even
}

// ---------------- kernel 0: prep (w2, sizes + scans, wtab, counter) ---------
__global__ void prep_kernel(const float* __restrict__ w, unsigned short* __restrict__ w2,
                            int* __restrict__ offsF, int* __restrict__ offsT,
                            int* __restrict__ wtab, int* __restrict__ counter) {
  const int tid = threadIdx.x;
  __shared__ int temp[256];
  if (tid == 0) *counter = 0;
  // w2[c16][o][kk] = bf16(w[o][i][k]) with ci=c16*16+kk, k=ci>>5, i=ci&31
  for (int idx = tid; idx < 14 * 32 * 16; idx += 256) {
    int kk = idx & 15; int o = (idx >> 4) & 31; int c16 = idx >> 9;
    int ci = c16 * 16 + kk; int i = ci & 31; int k = ci >> 5;
    w2[idx] = f2bf(w[(o * 32 + i) * 7 + k]);
  }
  for (int e = tid; e < NE; e += 256) {
    int t = e / 21, d = e % 21;
    int B = windowB(t, d);
    offsF[e] = (B >= 0) ? nsupOf(B) * 7 : 0;
    offsT[e] = 14 * widthOf(B);
  }
  for (int t = tid; t < 361; t += 256) {
    int Wt = 0;
    for (int d = 0; d < WLAT; ++d) {
      int B = windowB(t, d);
      if (B >= 0) Wt += ((31 + B) >> 4) + ((B + 15) >> 4) + 1;
    }
    wtab[t] = Wt;
  }
  __syncthreads();
  // two-level exclusive scan for offsF then offsT (chunk = 30, 256*30 >= NE)
#pragma unroll 1
  for (int pass = 0; pass < 2; ++pass) {
    int* a = pass ? offsT : offsF;
    int s = tid * 30, e = s + 30; if (e > NE) e = NE; if (s > NE) s = NE;
    int sum = 0;
    for (int i = s; i < e; ++i) sum += a[i];
    temp[tid] = sum;
    __syncthreads();
    if (tid == 0) {
      int run = 0;
      for (int i = 0; i < 256; ++i) { int v = temp[i]; temp[i] = run; run += v; }
      a[NE] = run;
    }
    __syncthreads();
    int run = temp[tid];
    for (int i = s; i < e; ++i) { int v = a[i]; a[i] = run; run += v; }
    __syncthreads();
  }
}

// ---------------- kernel 1: bilinear upsample -> tiled bf16 XT --------------
// XT[t][c][i][kk] with b = c*16+kk  (wave A-load = contiguous 1KB)
__global__ void upsample_kernel(const float* __restrict__ x,
                                unsigned short* __restrict__ XT) {
  int idx = blockIdx.x * 256 + threadIdx.x;
  if (idx >= NLAT_O * NC45 * 512) return;
  int kk = idx & 15;
  int i = (idx >> 4) & 31;
  int c = (idx >> 9) % NC45;
  int t = idx / (NC45 * 512);
  int p = c * 16 + kk;

  double post = (double)t * (239.0 / 360.0);
  int i0 = (int)floor(post);
  if (i0 < 0) i0 = 0;
  if (i0 > NLAT_I - 1) i0 = NLAT_I - 1;
  int i1 = i0 + 1; if (i1 > NLAT_I - 1) i1 = NLAT_I - 1;
  float wt = (float)(post - (double)i0);

  double posp = (double)p * (2.0 / 3.0);
  double j0f = floor(posp);
  int j0 = ((int)j0f) % NLON_I;
  int j1 = (j0 + 1) % NLON_I;
  float wp = (float)(posp - j0f);

  const float* xi = x + (size_t)i * (NLAT_I * NLON_I);
  float a = xi[i0 * NLON_I + j0];
  float b = xi[i0 * NLON_I + j1];
  float cc = xi[i1 * NLON_I + j0];
  float d = xi[i1 * NLON_I + j1];
  float l0 = (1.0f - wt) * a + wt * cc;
  float l1 = (1.0f - wt) * b + wt * d;
  XT[idx] = f2bf((1.0f - wp) * l0 + wp * l1);
}

// ---------------- kernel 2: raw psi (f32), evaluated ONCE -------------------
__global__ void psi_raw_kernel(const int* __restrict__ offsF,
                               float* __restrict__ PSIF) {
  int t = blockIdx.x, d = blockIdx.y;
  int B = windowB(t, d);
  if (B < 0) return;
  int nsup = nsupOf(B);
  int bLo = (B >= 360) ? -360 : -B;
  int offF = offsF[t * 21 + d];
  int tp = t + d - WOFF;
  float th = (float)t * DLAT_V, ga = (float)tp * DLAT_V;
  float st, ct, sg, cg;
  sincosf(th, &st, &ct);
  sincosf(ga, &sg, &cg);
  float q = sg * QF_V;
  for (int ix = threadIdx.x; ix < nsup; ix += 256) {
    float v[7];
    psi_eval(ct, st, cg, sg, q, (float)(bLo + ix) * DPHI_V, v);
#pragma unroll
    for (int k = 0; k < 7; ++k) PSIF[offF + k * nsup + ix] = v[k];
  }
}

// ---------------- kernel 3: per-(k,t) scales from raw psi (no trig) ---------
__global__ void reduce_kernel(const int* __restrict__ offsF,
                              const float* __restrict__ PSIF,
                              float* __restrict__ recip) {
  int t = blockIdx.x;
  int tid = threadIdx.x;
  float acc[7];
#pragma unroll
  for (int k = 0; k < 7; ++k) acc[k] = 0.0f;
  for (int d = 0; d < WLAT; ++d) {
    int B = windowB(t, d);
    if (B < 0) continue;
    int nsup = nsupOf(B);
    int offF = offsF[t * 21 + d];
    for (int ix = tid; ix < nsup; ix += 256) {
#pragma unroll
      for (int k = 0; k < 7; ++k) acc[k] += PSIF[offF + k * nsup + ix];
    }
  }
#pragma unroll
  for (int k = 0; k < 7; ++k) {
    float a = acc[k];
    for (int off = 32; off > 0; off >>= 1) a += __shfl_down(a, off, 64);
    acc[k] = a;
  }
  __shared__ float red[4][7];
  int wid = tid >> 6;
  if ((tid & 63) == 0) {
#pragma unroll
    for (int k = 0; k < 7; ++k) red[wid][k] = acc[k];
  }
  __syncthreads();
  if (tid == 0) {
#pragma unroll
    for (int k = 0; k < 7; ++k) {
      float s = red[0][k] + red[1][k] + red[2][k] + red[3][k];
      recip[t * 7 + k] = 1.0f / fmaxf(s, 1e-8f);
    }
  }
}

// ---------------- kernel 4: normalized bf16 Toeplitz (2 parity copies) ------
// per (t,d): rows (2k+sel), sel in {0,1}; T_sel[m] = psi(bLo + m + sel - PAD_T)
__global__ void psi_toep_kernel(const int* __restrict__ offsF,
                                const int* __restrict__ offsT,
                                const float* __restrict__ PSIF,
                                const float* __restrict__ recip,
                                unsigned short* __restrict__ PSIT) {
  int t = blockIdx.x, d = blockIdx.y;
  int B = windowB(t, d);
  if (B < 0) return;
  int nsup = nsupOf(B);
  int width = widthOf(B);
  int offF = offsF[t * 21 + d];
  int offT = offsT[t * 21 + d];
  float rc[7];
#pragma unroll
  for (int k = 0; k < 7; ++k) rc[k] = recip[t * 7 + k];
  for (int ix = threadIdx.x; ix <= width; ix += 256) {
    int isup = ix - PAD_T;
    unsigned short vv[7];
    if (isup >= 0 && isup < nsup) {
#pragma unroll
      for (int k = 0; k < 7; ++k)
        vv[k] = f2bf(PSIF[offF + k * nsup + isup] * rc[k]);
    } else {
#pragma unroll
      for (int k = 0; k < 7; ++k) vv[k] = 0;
    }
    if (ix < width) {
#pragma unroll
      for (int k = 0; k < 7; ++k) PSIT[offT + (2 * k) * width + ix] = vv[k];
    }
    if (ix >= 1) {
#pragma unroll
      for (int k = 0; k < 7; ++k) PSIT[offT + (2 * k + 1) * width + ix - 1] = vv[k];
    }
  }
}

// ---------------- kernel 5: persistent MFMA conv + channel MFMA -------------
#define MAC1(KK, ACC) {                                                   \
    short8v Bf = *(const short8v*)(bp + (KK) * ks);                       \
    ACC = __builtin_amdgcn_mfma_f32_32x32x16_bf16(A, Bf, ACC, 0, 0, 0); }

#define DUMPQ(RR) {                                                       \
    int iq = ((RR) & 3) + 8 * ((RR) >> 2) + 4 * g;                        \
    int base = nn * 16 + (iq & 15);                                       \
    b2[0*512+base] = f2bf(acc0[RR]); b2[1*512+base] = f2bf(acc1[RR]);     \
    b2[2*512+base] = f2bf(acc2[RR]); b2[3*512+base] = f2bf(acc3[RR]);     \
    b2[4*512+base] = f2bf(acc4[RR]); b2[5*512+base] = f2bf(acc5[RR]);     \
    b2[6*512+base] = f2bf(acc6[RR]); }

__global__ __launch_bounds__(256, 3) void disco_kernel(
    const unsigned short* __restrict__ XT, const unsigned short* __restrict__ PSIT,
    const unsigned short* __restrict__ w2g, const int* __restrict__ offsT,
    const int* __restrict__ wtab, float* __restrict__ y,
    int* __restrict__ counter) {
  const int tid = threadIdx.x;
  __shared__ __align__(16) unsigned short b2all[4 * 3584];
  __shared__ int Sbuf[362];
  __shared__ int sB[WLAT], sUc[WLAT + 1], sOff[WLAT], sW[WLAT];
  __shared__ int curItem;

  // ---- schedule (no trig: wtab precomputed) ----
  for (int j = tid; j < 361; j += 256) {
    int t = (j & 1) ? 360 - (j >> 1) : (j >> 1);   // poles first
    Sbuf[j] = 6 * ((wtab[t] + CT - 1) / CT);
  }
  __syncthreads();
  if (tid == 0) {
    int run = 0;
    for (int j = 0; j < 361; ++j) { int v = Sbuf[j]; Sbuf[j] = run; run += v; }
    Sbuf[361] = run;
  }
  __syncthreads();
  const int NTOT = Sbuf[361];

  const int lane = tid & 63, wv = tid >> 6, nn = lane & 31, g = lane >> 5;
  const int g8 = g * 8;
  const int laneA = nn * 16 + g8;
  const int lconst = g8 - nn;

  while (true) {
    if (tid == 0) curItem = atomicAdd(counter, 1);
    __syncthreads();   // also protects sB/sUc from previous item's readers
    const int m = curItem;
    if (m >= NTOT) break;

    int lo = 0, hi = 360;
    while (lo < hi) {
      int mid = (lo + hi + 1) >> 1;
      if (Sbuf[mid] <= m) lo = mid; else hi = mid - 1;
    }
    const int j = lo;
    const int r = m - Sbuf[j];
    const int t = (j & 1) ? 360 - (j >> 1) : (j >> 1);
    const int pgroup = r % 6;
    const int part = r / 6;

    if (tid < WLAT) {
      int B = windowB(t, tid);
      sB[tid] = B;
      sOff[tid] = offsT[t * 21 + tid];
      sW[tid] = widthOf(B);
    }
    __syncthreads();
    if (tid == 0) {
      int run = 0; sUc[0] = 0;
      for (int d = 0; d < WLAT; ++d) {
        int B = sB[d];
        int np = (B >= 0) ? ((31 + B) >> 4) + ((B + 15) >> 4) + 1 : 0;
        run += np; sUc[d + 1] = run;
      }
    }
    __syncthreads();
    const int Wt = sUc[WLAT];
    int g0 = part * CT, g1 = g0 + CT;
    if (g1 > Wt) g1 = Wt;

    const int ptile = pgroup * 4 + wv;   // 0..23 (23 = dead pad tile)
    const int pw = ptile * 32;
    const int pw16 = ptile * 2;

    f32x16 acc0, acc1, acc2, acc3, acc4, acc5, acc6;
#pragma unroll
    for (int z = 0; z < 16; ++z) {
      acc0[z]=0; acc1[z]=0; acc2[z]=0; acc3[z]=0; acc4[z]=0; acc5[z]=0; acc6[z]=0;
    }

    int dcur = -1, bLo = 0, cmin = 0, tpd = 0, wdt = 0, ks = 0;
    const unsigned short* pbase = PSIT;
    for (int gi = g0; gi < g1; ++gi) {
      int d = (dcur < 0) ? 0 : dcur;
      while (sUc[d + 1] <= gi) ++d;
      if (d != dcur) {
        dcur = d;
        int B = sB[d];
        bLo = (B >= 360) ? -360 : -B;
        cmin = -((B + 15) >> 4);
        tpd = t + d - WOFF;
        wdt = sW[d];
        ks = 2 * wdt;
        pbase = PSIT + sOff[d];
      }
      const int c = cmin + (gi - sUc[d]);
      int v45 = pw16 + c;
      if (v45 < 0) v45 += NC45;
      if (v45 >= NC45) v45 -= NC45;
      const unsigned short* ap = XT + (((size_t)tpd * NC45 + v45) << 9) + laneA;
      short8v A = *(const short8v*)ap;
      int jbIdx = c * 16 + lconst - bLo + PAD_T;
      int sel = jbIdx & 1;
      int moff = jbIdx + (sel ? (wdt - 1) : 0);   // parity copy keeps 4B align
      const unsigned short* bp = pbase + moff;
      MAC1(0, acc0) MAC1(1, acc1) MAC1(2, acc2) MAC1(3, acc3)
      MAC1(4, acc4) MAC1(5, acc5) MAC1(6, acc6)
    }

    // ---- GEMM2: y[o,p] = sum_{ci=(k,i)} w2[o,ci] * G[ci,p] (wave-private) --
    unsigned short* b2 = b2all + wv * 3584;
    f32x16 Dy;
#pragma unroll
    for (int z = 0; z < 16; ++z) Dy[z] = 0.0f;

    {  // half 0: i in [0,16) <-> regs 0..7
#pragma unroll
      for (int q2 = 0; q2 < 8; ++q2) { DUMPQ(q2) }
#pragma unroll
      for (int k2 = 0; k2 < 7; ++k2) {
        short8v A2 = *(const short8v*)(w2g + (((2 * k2 + 0) * 32 + nn) << 4) + g8);
        short8v B2f = *(const short8v*)(b2 + (k2 << 9) + (nn << 4) + g8);
        Dy = __builtin_amdgcn_mfma_f32_32x32x16_bf16(A2, B2f, Dy, 0, 0, 0);
      }
    }
    {  // half 1: i in [16,32) <-> regs 8..15
#pragma unroll
      for (int q2 = 8; q2 < 16; ++q2) { DUMPQ(q2) }
#pragma unroll
      for (int k2 = 0; k2 < 7; ++k2) {
        short8v A2 = *(const short8v*)(w2g + (((2 * k2 + 1) * 32 + nn) << 4) + g8);
        short8v B2f = *(const short8v*)(b2 + (k2 << 9) + (nn << 4) + g8);
        Dy = __builtin_amdgcn_mfma_f32_32x32x16_bf16(A2, B2f, Dy, 0, 0, 0);
      }
    }

    const int p = pw + nn;
    if (p < NLON_O) {
#pragma unroll
      for (int rr = 0; rr < 16; ++rr) {
        int o = (rr & 3) + 8 * (rr >> 2) + 4 * g;
        atomicAdd(&y[((size_t)o * NLAT_O + t) * NLON_O + p], Dy[rr]);
      }
    }
  }
}

// ---------------- launch ----------------------------------------------------
extern "C" void kernel_launch(void* const* d_in, const int* in_sizes, int n_in,
                              void* d_out, int out_size, void* d_ws, size_t ws_size,
                              hipStream_t stream) {
  (void)in_sizes; (void)n_in; (void)out_size; (void)ws_size;
  const float* x = (const float*)d_in[0];
  const float* w = (const float*)d_in[1];
  float* y = (float*)d_out;

  // ws: XT (16.6MB) | PSIF f32 (24MB cap) | PSIT bf16 (52MB cap) | small tables
  unsigned short* XT = (unsigned short*)d_ws;                 // 8,317,440 shorts
  float* PSIF = (float*)(XT + (size_t)NLAT_O * NC45 * 512);   // cap 6e6 f32
  unsigned short* PSIT = (unsigned short*)(PSIF + 6000000);   // cap 26e6 shorts
  unsigned short* w2 = PSIT + 26000000;                       // 7168
  float* recip = (float*)(w2 + 7168);                         // 2527
  int* offsF = (int*)(recip + NLAT_O * K_N);                  // NE+1
  int* offsT = offsF + NE + 1;                                // NE+1
  int* wtab = offsT + NE + 1;                                 // 361
  int* counter = wtab + 361;                                  // 1

  hipMemsetAsync(y, 0, (size_t)CO_N * NLAT_O * NLON_O * sizeof(float), stream);

  prep_kernel<<<1, 256, 0, stream>>>(w, w2, offsF, offsT, wtab, counter);
  int n_up = NLAT_O * NC45 * 512;
  upsample_kernel<<<(n_up + 255) / 256, 256, 0, stream>>>(x, XT);
  psi_raw_kernel<<<dim3(NLAT_O, WLAT), 256, 0, stream>>>(offsF, PSIF);
  reduce_kernel<<<NLAT_O, 256, 0, stream>>>(offsF, PSIF, recip);
  psi_toep_kernel<<<dim3(NLAT_O, WLAT), 256, 0, stream>>>(offsF, offsT, PSIF, recip, PSIT);
  disco_kernel<<<NBLK, 256, 0, stream>>>(XT, PSIT, w2, offsT, wtab, y, counter);
}

// Round 8
// 540.890 us; speedup vs baseline: 4.1822x; 1.6529x over previous
//
#include <hip/hip_runtime.h>
#include <hip/hip_bf16.h>
#include <math.h>

#define NLAT_I 240
#define NLON_I 480
#define NLAT_O 361
#define NLON_O 720
#define CI_N 32
#define CO_N 32
#define K_N 7
#define WOFF 10
#define WLAT 21

#define PI_F 3.14159265358979323846f
#define TWOPI_F 6.28318530717958647692f
#define DLAT_V (PI_F / 360.0f)
#define DPHI_V (TWOPI_F / 720.0f)
#define CUTOFF_V (3.25f * PI_F / 120.0f)
#define DR_V (CUTOFF_V / 3.0f)
#define IDR_V (1.0f / DR_V)
#define DPH_V (TWOPI_F / 3.0f)
#define IDPH_V (1.0f / DPH_V)
#define QF_V (DLAT_V * DPHI_V)

#define PAD_T 64        // Toeplitz pad (covers fragment reach beyond support)
#define CT 64           // positions per work item
#define NBLK 512
#define NC45 45         // 720/16 column chunks
#define NE 7581         // 361*21

typedef __attribute__((ext_vector_type(8))) short short8v;
typedef __attribute__((ext_vector_type(16))) float f32x16;

__device__ __forceinline__ unsigned short f2bf(float f) {
  __hip_bfloat16 h = __float2bfloat16(f);   // RTNE
  union { __hip_bfloat16 b; unsigned short s; } u; u.b = h; return u.s;
}

// ---------------- psi evaluation --------------------------------------------
__device__ __forceinline__ void psi_eval(float ct, float st, float cg, float sg,
                                         float q, float bang, float v[7]) {
  float sb, cb;
  sincosf(bang, &sb, &cb);
  float dx = sg * cb - st;
  float dy = sg * sb;
  float dz = cg - ct;
  float c2 = dx * dx + dy * dy + dz * dz;
  float r = 2.0f * asinf(fminf(1.0f, 0.5f * sqrtf(c2)));
  if (r <= CUTOFF_V) {
    float xx = ct * cb * sg - st * cg;
    float yy = sb * sg;
    float phi = atan2f(yy, xx);
    if (phi < 0.0f) phi += TWOPI_F;
    v[0] = fmaxf(0.0f, 1.0f - r * IDR_V) * q;
#pragma unroll
    for (int k = 1; k < 7; ++k) {
      const float irdr = (float)(1 + (k - 1) / 3) * DR_V;
      const float ipph = (float)((k - 1) % 3) * DPH_V;
      float rad = fmaxf(0.0f, 1.0f - fabsf(r - irdr) * IDR_V);
      float dd = fabsf(phi - ipph);
      dd = fminf(dd, TWOPI_F - dd);
      float az = fmaxf(0.0f, 1.0f - dd * IDPH_V);
      v[k] = rad * az * q;
    }
  } else {
#pragma unroll
    for (int k = 0; k < 7; ++k) v[k] = 0.0f;
  }
}

// per-(t,d) lon window half-width: -1 empty, 360 full circle
__device__ __forceinline__ int windowB(int t, int d) {
  int tp = t + d - WOFF;
  if (tp < 0 || tp > NLAT_O - 1) return -1;
  float th = (float)t * DLAT_V, ga = (float)tp * DLAT_V;
  float st = sinf(th), ct = cosf(th), sg = sinf(ga), cg = cosf(ga);
  float den = st * sg;
  float num = cosf(CUTOFF_V) - ct * cg;
  if (den < 1e-9f) return (fabsf(th - ga) <= CUTOFF_V) ? 360 : -1;
  if (num >= den) return -1;
  if (num <= -den) return 360;
  int B = (int)ceilf(acosf(num / den) * (1.0f / DPHI_V)) + 1;  // +1 margin; psi masks
  return B > 360 ? 360 : B;
}

__device__ __forceinline__ int nsupOf(int B) { return (B >= 360) ? 720 : 2 * B + 1; }
__device__ __forceinline__ int widthOf(int B) {
  return (B < 0) ? 0 : ((nsupOf(B) + 129) & ~1);   // even
}

// ---------------- kernel 0: prep (w2, scans, wtab, sums=0, counter) ---------
__global__ void prep_kernel(const float* __restrict__ w, unsigned short* __restrict__ w2,
                            int* __restrict__ offsF, int* __restrict__ offsT,
                            int* __restrict__ wtab, float* __restrict__ sums,
                            int* __restrict__ counter) {
  const int tid = threadIdx.x;
  __shared__ int temp[256];
  if (tid == 0) *counter = 0;
  for (int idx = tid; idx < 361 * 7; idx += 256) sums[idx] = 0.0f;
  // w2[c16][o][kk] = bf16(w[o][i][k]) with ci=c16*16+kk, k=ci>>5, i=ci&31
  for (int idx = tid; idx < 14 * 32 * 16; idx += 256) {
    int kk = idx & 15; int o = (idx >> 4) & 31; int c16 = idx >> 9;
    int ci = c16 * 16 + kk; int i = ci & 31; int k = ci >> 5;
    w2[idx] = f2bf(w[(o * 32 + i) * 7 + k]);
  }
  for (int e = tid; e < NE; e += 256) {
    int t = e / 21, d = e % 21;
    int B = windowB(t, d);
    offsF[e] = (B >= 0) ? nsupOf(B) * 7 : 0;
    offsT[e] = 14 * widthOf(B);
  }
  for (int t = tid; t < 361; t += 256) {
    int Wt = 0;
    for (int d = 0; d < WLAT; ++d) {
      int B = windowB(t, d);
      if (B >= 0) Wt += ((31 + B) >> 4) + ((B + 15) >> 4) + 1;
    }
    wtab[t] = Wt;
  }
  __syncthreads();
  // two-level exclusive scan for offsF then offsT (chunk = 30, 256*30 >= NE)
#pragma unroll 1
  for (int pass = 0; pass < 2; ++pass) {
    int* a = pass ? offsT : offsF;
    int s = tid * 30, e = s + 30; if (e > NE) e = NE; if (s > NE) s = NE;
    int sum = 0;
    for (int i = s; i < e; ++i) sum += a[i];
    temp[tid] = sum;
    __syncthreads();
    if (tid == 0) {
      int run = 0;
      for (int i = 0; i < 256; ++i) { int v = temp[i]; temp[i] = run; run += v; }
      a[NE] = run;
    }
    __syncthreads();
    int run = temp[tid];
    for (int i = s; i < e; ++i) { int v = a[i]; a[i] = run; run += v; }
    __syncthreads();
  }
}

// ---------------- kernel 1: bilinear upsample -> tiled bf16 XT --------------
// XT[t][c][i][kk] with b = c*16+kk  (wave A-load = contiguous 1KB)
__global__ void upsample_kernel(const float* __restrict__ x,
                                unsigned short* __restrict__ XT) {
  int idx = blockIdx.x * 256 + threadIdx.x;
  if (idx >= NLAT_O * NC45 * 512) return;
  int kk = idx & 15;
  int i = (idx >> 4) & 31;
  int c = (idx >> 9) % NC45;
  int t = idx / (NC45 * 512);
  int p = c * 16 + kk;

  double post = (double)t * (239.0 / 360.0);
  int i0 = (int)floor(post);
  if (i0 < 0) i0 = 0;
  if (i0 > NLAT_I - 1) i0 = NLAT_I - 1;
  int i1 = i0 + 1; if (i1 > NLAT_I - 1) i1 = NLAT_I - 1;
  float wt = (float)(post - (double)i0);

  double posp = (double)p * (2.0 / 3.0);
  double j0f = floor(posp);
  int j0 = ((int)j0f) % NLON_I;
  int j1 = (j0 + 1) % NLON_I;
  float wp = (float)(posp - j0f);

  const float* xi = x + (size_t)i * (NLAT_I * NLON_I);
  float a = xi[i0 * NLON_I + j0];
  float b = xi[i0 * NLON_I + j1];
  float cc = xi[i1 * NLON_I + j0];
  float d = xi[i1 * NLON_I + j1];
  float l0 = (1.0f - wt) * a + wt * cc;
  float l1 = (1.0f - wt) * b + wt * d;
  XT[idx] = f2bf((1.0f - wp) * l0 + wp * l1);
}

// ---------------- kernel 2: raw psi (f32) + fused per-(k,t) partial sums ----
__global__ void psi_raw_kernel(const int* __restrict__ offsF,
                               float* __restrict__ PSIF,
                               float* __restrict__ sums) {
  int t = blockIdx.x, d = blockIdx.y;
  int B = windowB(t, d);
  if (B < 0) return;
  int nsup = nsupOf(B);
  int bLo = (B >= 360) ? -360 : -B;
  int offF = offsF[t * 21 + d];
  int tp = t + d - WOFF;
  float th = (float)t * DLAT_V, ga = (float)tp * DLAT_V;
  float st, ct, sg, cg;
  sincosf(th, &st, &ct);
  sincosf(ga, &sg, &cg);
  float q = sg * QF_V;
  float acc[7];
#pragma unroll
  for (int k = 0; k < 7; ++k) acc[k] = 0.0f;
  for (int ix = threadIdx.x; ix < nsup; ix += 256) {
    float v[7];
    psi_eval(ct, st, cg, sg, q, (float)(bLo + ix) * DPHI_V, v);
#pragma unroll
    for (int k = 0; k < 7; ++k) { PSIF[offF + k * nsup + ix] = v[k]; acc[k] += v[k]; }
  }
#pragma unroll
  for (int k = 0; k < 7; ++k) {
    float a = acc[k];
    for (int off = 32; off > 0; off >>= 1) a += __shfl_down(a, off, 64);
    acc[k] = a;
  }
  __shared__ float red[4][7];
  int wid = threadIdx.x >> 6;
  if ((threadIdx.x & 63) == 0) {
#pragma unroll
    for (int k = 0; k < 7; ++k) red[wid][k] = acc[k];
  }
  __syncthreads();
  if (threadIdx.x == 0) {
#pragma unroll
    for (int k = 0; k < 7; ++k)
      atomicAdd(&sums[t * 7 + k], red[0][k] + red[1][k] + red[2][k] + red[3][k]);
  }
}

// ---------------- kernel 3: normalized bf16 Toeplitz (2 parity copies) ------
__global__ void psi_toep_kernel(const int* __restrict__ offsF,
                                const int* __restrict__ offsT,
                                const float* __restrict__ PSIF,
                                const float* __restrict__ sums,
                                unsigned short* __restrict__ PSIT) {
  int t = blockIdx.x, d = blockIdx.y;
  int B = windowB(t, d);
  if (B < 0) return;
  int nsup = nsupOf(B);
  int width = widthOf(B);
  int offF = offsF[t * 21 + d];
  int offT = offsT[t * 21 + d];
  float rc[7];
#pragma unroll
  for (int k = 0; k < 7; ++k) rc[k] = 1.0f / fmaxf(sums[t * 7 + k], 1e-8f);
  for (int ix = threadIdx.x; ix <= width; ix += 256) {
    int isup = ix - PAD_T;
    unsigned short vv[7];
    if (isup >= 0 && isup < nsup) {
#pragma unroll
      for (int k = 0; k < 7; ++k)
        vv[k] = f2bf(PSIF[offF + k * nsup + isup] * rc[k]);
    } else {
#pragma unroll
      for (int k = 0; k < 7; ++k) vv[k] = 0;
    }
    if (ix < width) {
#pragma unroll
      for (int k = 0; k < 7; ++k) PSIT[offT + (2 * k) * width + ix] = vv[k];
    }
    if (ix >= 1) {
#pragma unroll
      for (int k = 0; k < 7; ++k) PSIT[offT + (2 * k + 1) * width + ix - 1] = vv[k];
    }
  }
}

// ---------------- kernel 4: persistent pipelined MFMA conv + channel MFMA ---
#define LOADSET(S, CC) {                                                  \
    int v45 = pw16 + (CC);                                                \
    if (v45 < 0) v45 += NC45;                                             \
    if (v45 >= NC45) v45 -= NC45;                                         \
    A##S = *(const short8v*)(XT + (((size_t)tpd * NC45 + v45) << 9) + laneA); \
    int jbIdx = (CC) * 16 + lconst - bLo + PAD_T;                         \
    const unsigned short* bp = pbase + jbIdx + ((jbIdx & 1) ? (wdt - 1) : 0); \
    B##S##0 = *(const short8v*)(bp);                                      \
    B##S##1 = *(const short8v*)(bp + ks);                                 \
    B##S##2 = *(const short8v*)(bp + 2 * ks);                             \
    B##S##3 = *(const short8v*)(bp + 3 * ks);                             \
    B##S##4 = *(const short8v*)(bp + 4 * ks);                             \
    B##S##5 = *(const short8v*)(bp + 5 * ks);                             \
    B##S##6 = *(const short8v*)(bp + 6 * ks); }

#define MFMASET(S) {                                                      \
    acc0 = __builtin_amdgcn_mfma_f32_32x32x16_bf16(A##S, B##S##0, acc0, 0, 0, 0); \
    acc1 = __builtin_amdgcn_mfma_f32_32x32x16_bf16(A##S, B##S##1, acc1, 0, 0, 0); \
    acc2 = __builtin_amdgcn_mfma_f32_32x32x16_bf16(A##S, B##S##2, acc2, 0, 0, 0); \
    acc3 = __builtin_amdgcn_mfma_f32_32x32x16_bf16(A##S, B##S##3, acc3, 0, 0, 0); \
    acc4 = __builtin_amdgcn_mfma_f32_32x32x16_bf16(A##S, B##S##4, acc4, 0, 0, 0); \
    acc5 = __builtin_amdgcn_mfma_f32_32x32x16_bf16(A##S, B##S##5, acc5, 0, 0, 0); \
    acc6 = __builtin_amdgcn_mfma_f32_32x32x16_bf16(A##S, B##S##6, acc6, 0, 0, 0); }

#define DUMPQ(RR) {                                                       \
    int iq = ((RR) & 3) + 8 * ((RR) >> 2) + 4 * g;                        \
    int base = nn * 16 + (iq & 15);                                       \
    b2[0*512+base] = f2bf(acc0[RR]); b2[1*512+base] = f2bf(acc1[RR]);     \
    b2[2*512+base] = f2bf(acc2[RR]); b2[3*512+base] = f2bf(acc3[RR]);     \
    b2[4*512+base] = f2bf(acc4[RR]); b2[5*512+base] = f2bf(acc5[RR]);     \
    b2[6*512+base] = f2bf(acc6[RR]); }

__global__ __launch_bounds__(256, 2) void disco_kernel(
    const unsigned short* __restrict__ XT, const unsigned short* __restrict__ PSIT,
    const unsigned short* __restrict__ w2g, const int* __restrict__ offsT,
    const int* __restrict__ wtab, float* __restrict__ y,
    int* __restrict__ counter) {
  const int tid = threadIdx.x;
  __shared__ __align__(16) unsigned short b2all[4 * 3584];
  __shared__ int Sbuf[362];
  __shared__ int sB[WLAT], sUc[WLAT + 1], sOff[WLAT], sW[WLAT];
  __shared__ int curItem;

  // ---- schedule (no trig: wtab precomputed) ----
  for (int j = tid; j < 361; j += 256) {
    int t = (j & 1) ? 360 - (j >> 1) : (j >> 1);   // poles first
    Sbuf[j] = 6 * ((wtab[t] + CT - 1) / CT);
  }
  __syncthreads();
  if (tid == 0) {
    int run = 0;
    for (int j = 0; j < 361; ++j) { int v = Sbuf[j]; Sbuf[j] = run; run += v; }
    Sbuf[361] = run;
  }
  __syncthreads();
  const int NTOT = Sbuf[361];

  const int lane = tid & 63, wv = tid >> 6, nn = lane & 31, g = lane >> 5;
  const int g8 = g * 8;
  const int laneA = nn * 16 + g8;
  const int lconst = g8 - nn;

  while (true) {
    if (tid == 0) curItem = atomicAdd(counter, 1);
    __syncthreads();   // also protects sB/sUc from previous item's readers
    const int m = curItem;
    if (m >= NTOT) break;

    int lo = 0, hi = 360;
    while (lo < hi) {
      int mid = (lo + hi + 1) >> 1;
      if (Sbuf[mid] <= m) lo = mid; else hi = mid - 1;
    }
    const int j = lo;
    const int r = m - Sbuf[j];
    const int t = (j & 1) ? 360 - (j >> 1) : (j >> 1);
    const int pgroup = r % 6;
    const int part = r / 6;

    if (tid < WLAT) {
      int B = windowB(t, tid);
      sB[tid] = B;
      sOff[tid] = offsT[t * 21 + tid];
      sW[tid] = widthOf(B);
    }
    __syncthreads();
    if (tid == 0) {
      int run = 0; sUc[0] = 0;
      for (int d = 0; d < WLAT; ++d) {
        int B = sB[d];
        int np = (B >= 0) ? ((31 + B) >> 4) + ((B + 15) >> 4) + 1 : 0;
        run += np; sUc[d + 1] = run;
      }
    }
    __syncthreads();
    const int Wt = sUc[WLAT];
    int g0 = part * CT, g1 = g0 + CT;
    if (g1 > Wt) g1 = Wt;

    const int ptile = pgroup * 4 + wv;   // 0..23 (23 = dead pad tile)
    const int pw = ptile * 32;
    const int pw16 = ptile * 2;

    f32x16 acc0, acc1, acc2, acc3, acc4, acc5, acc6;
#pragma unroll
    for (int z = 0; z < 16; ++z) {
      acc0[z]=0; acc1[z]=0; acc2[z]=0; acc3[z]=0; acc4[z]=0; acc5[z]=0; acc6[z]=0;
    }

    // ---- hot loop: d-runs with 2-stage software pipeline ----
    short8v A0, A1;
    short8v B00, B01, B02, B03, B04, B05, B06;
    short8v B10, B11, B12, B13, B14, B15, B16;

    int gi = g0;
    int d = 0;
    while (d < WLAT && sUc[d + 1] <= gi) ++d;
    while (gi < g1) {
      const int B = sB[d];
      const int bLo = (B >= 360) ? -360 : -B;
      const int cmin = -((B + 15) >> 4);
      const int tpd = t + d - WOFF;
      const int wdt = sW[d];
      const int ks = 2 * wdt;
      const unsigned short* pbase = PSIT + sOff[d];
      const int rend = sUc[d + 1];
      const int gend = (rend < g1) ? rend : g1;
      const int n = gend - gi;
      int c = cmin + (gi - sUc[d]);

      LOADSET(0, c)
      int it = 0;
      for (; it + 2 <= n; it += 2) {
        LOADSET(1, c + 1)
        MFMASET(0)
        if (it + 2 < n) { LOADSET(0, c + 2) }
        MFMASET(1)
        c += 2;
      }
      if (it < n) { MFMASET(0) }

      gi = gend;
      ++d;
      while (d < WLAT && sUc[d + 1] <= gi) ++d;
    }

    // ---- GEMM2: y[o,p] = sum_{ci=(k,i)} w2[o,ci] * G[ci,p] (wave-private) --
    unsigned short* b2 = b2all + wv * 3584;
    f32x16 Dy;
#pragma unroll
    for (int z = 0; z < 16; ++z) Dy[z] = 0.0f;

    {  // half 0: i in [0,16) <-> regs 0..7
#pragma unroll
      for (int q2 = 0; q2 < 8; ++q2) { DUMPQ(q2) }
#pragma unroll
      for (int k2 = 0; k2 < 7; ++k2) {
        short8v A2 = *(const short8v*)(w2g + (((2 * k2 + 0) * 32 + nn) << 4) + g8);
        short8v B2f = *(const short8v*)(b2 + (k2 << 9) + (nn << 4) + g8);
        Dy = __builtin_amdgcn_mfma_f32_32x32x16_bf16(A2, B2f, Dy, 0, 0, 0);
      }
    }
    {  // half 1: i in [16,32) <-> regs 8..15
#pragma unroll
      for (int q2 = 8; q2 < 16; ++q2) { DUMPQ(q2) }
#pragma unroll
      for (int k2 = 0; k2 < 7; ++k2) {
        short8v A2 = *(const short8v*)(w2g + (((2 * k2 + 1) * 32 + nn) << 4) + g8);
        short8v B2f = *(const short8v*)(b2 + (k2 << 9) + (nn << 4) + g8);
        Dy = __builtin_amdgcn_mfma_f32_32x32x16_bf16(A2, B2f, Dy, 0, 0, 0);
      }
    }

    const int p = pw + nn;
    if (p < NLON_O) {
#pragma unroll
      for (int rr = 0; rr < 16; ++rr) {
        int o = (rr & 3) + 8 * (rr >> 2) + 4 * g;
        atomicAdd(&y[((size_t)o * NLAT_O + t) * NLON_O + p], Dy[rr]);
      }
    }
  }
}

// ---------------- launch ----------------------------------------------------
extern "C" void kernel_launch(void* const* d_in, const int* in_sizes, int n_in,
                              void* d_out, int out_size, void* d_ws, size_t ws_size,
                              hipStream_t stream) {
  (void)in_sizes; (void)n_in; (void)out_size; (void)ws_size;
  const float* x = (const float*)d_in[0];
  const float* w = (const float*)d_in[1];
  float* y = (float*)d_out;

  // ws: XT (16.6MB) | PSIF f32 (24MB cap) | PSIT bf16 (52MB cap) | small tables
  unsigned short* XT = (unsigned short*)d_ws;                 // 8,317,440 shorts
  float* PSIF = (float*)(XT + (size_t)NLAT_O * NC45 * 512);   // cap 6e6 f32
  unsigned short* PSIT = (unsigned short*)(PSIF + 6000000);   // cap 26e6 shorts
  unsigned short* w2 = PSIT + 26000000;                       // 7168
  float* sums = (float*)(w2 + 7168);                          // 2527
  int* offsF = (int*)(sums + NLAT_O * K_N);                   // NE+1
  int* offsT = offsF + NE + 1;                                // NE+1
  int* wtab = offsT + NE + 1;                                 // 361
  int* counter = wtab + 361;                                  // 1

  hipMemsetAsync(y, 0, (size_t)CO_N * NLAT_O * NLON_O * sizeof(float), stream);

  prep_kernel<<<1, 256, 0, stream>>>(w, w2, offsF, offsT, wtab, sums, counter);
  int n_up = NLAT_O * NC45 * 512;
  upsample_kernel<<<(n_up + 255) / 256, 256, 0, stream>>>(x, XT);
  psi_raw_kernel<<<dim3(NLAT_O, WLAT), 256, 0, stream>>>(offsF, PSIF, sums);
  psi_toep_kernel<<<dim3(NLAT_O, WLAT), 256, 0, stream>>>(offsF, offsT, PSIF, sums, PSIT);
  disco_kernel<<<NBLK, 256, 0, stream>>>(XT, PSIT, w2, offsT, wtab, y, counter);
}